// Round 6
// baseline (243.205 us; speedup 1.0000x reference)
//
#include <hip/hip_runtime.h>
#include <hip/hip_bf16.h>

static constexpr int C  = 21;
static constexpr int H  = 384;
static constexpr int W  = 384;
static constexpr int HW = H * W;
static constexpr float NCLIQ = 5.0f;

typedef unsigned short u16;
typedef unsigned int   u32;

// function-local constexpr taps: exp(-o^2/18), o=-6..6 — folds to immediates
#define GKDEF constexpr float gk[13] = { \
    0.13533528f, 0.24935222f, 0.41111229f, 0.60653066f, 0.80073740f, \
    0.94595947f, 1.00000000f, 0.94595947f, 0.80073740f, 0.60653066f, \
    0.41111229f, 0.24935222f, 0.13533528f }

__device__ __forceinline__ float bfu2f(u16 u) {
    return __uint_as_float(((u32)u) << 16);
}
__device__ __forceinline__ u16 f2bfu(float f) {
    unsigned x = __float_as_uint(f);
    return (u16)((x + 0x7FFF + ((x >> 16) & 1)) >> 16);   // RNE; inputs finite
}

// ---- prep: q/un planar + wtab + norms + msum + M1/M2 + eq-flag + ST(it 0) ---
// R6: rgb taps read a 6-row LDS stage (coalesced float4 fill) instead of 75
// scattered 12B-stride global loads per thread.
__global__ __launch_bounds__(256)
void k_prep(const float* __restrict__ un, const float* __restrict__ rgb,
            const int* __restrict__ sp,
            const float* __restrict__ Wsp, const float* __restrict__ Wbi,
            const float* __restrict__ Cm,
            float* __restrict__ q, float* __restrict__ unp,
            u16* __restrict__ wtab, float* __restrict__ msum,
            float* __restrict__ inv_sp, float* __restrict__ inv_bn,
            float* __restrict__ M1, float* __restrict__ M2,
            int* __restrict__ mflag,
            u16* __restrict__ t1, u16* __restrict__ t2) {
    GKDEF;
    __shared__ float sM1[C * C], sM2[C * C];
    __shared__ float Aun[256 * C];          // coalesced un stage (21504 B)
    __shared__ float Argb[6 * W * 3];       // 6 full rgb rows    (27648 B)
    __shared__ int seq;
    if (threadIdx.x == 0) seq = 1;
    // every block computes M = Cm@W itself (no cross-block race); block 0
    // also publishes the global copy + the M1==M2 flag for later dispatches
    bool bad = false;
    for (int i = threadIdx.x; i < C * C; i += 256) {
        int c = i / C, k = i - c * C;
        float a1 = 0.f, a2 = 0.f;
        for (int j = 0; j < C; j++) {
            float cm = Cm[c * C + j];
            a1 += cm * Wsp[j * C + k];
            a2 += cm * Wbi[j * C + k];
        }
        sM1[i] = a1;
        sM2[i] = a2;
        if (__float_as_uint(a1) != __float_as_uint(a2)) bad = true;
        if (blockIdx.x == 0) { M1[i] = a1; M2[i] = a2; }
    }

    int bid = blockIdx.x;                       // 576, XCD-swizzled
    int chunk = (bid & 7) * 72 + (bid >> 3);
    int p0 = chunk * 256;
    int p = p0 + threadIdx.x;
    int y = p / W, x = p - y * W;
    int y0row = p0 / W;                         // block pixel rows: y0row..+1

    // stage un[p0*C .. (p0+256)*C) via coalesced float4 (was stride-84B gather)
    {
        const float* ub = un + (size_t)p0 * C;
        for (int i = threadIdx.x; i < 256 * C / 4; i += 256)
            *(float4*)(Aun + i * 4) = *(const float4*)(ub + i * 4);
    }
    // stage rgb rows y0row-2 .. y0row+3 (full width, coalesced). OOB rows are
    // left unwritten — tap loop bounds-guards sy so they are never read.
    for (int r = 0; r < 6; r++) {
        int gy = y0row - 2 + r;
        if (gy < 0 || gy >= H) continue;
        const float* src = rgb + (size_t)gy * W * 3;
        for (int i = threadIdx.x; i < W * 3 / 4; i += 256)
            *(float4*)(Argb + r * (W * 3) + i * 4) = *(const float4*)(src + i * 4);
    }
    __syncthreads();          // Aun + Argb + sM + seq-init ready
    if (bad) atomicAnd(&seq, 0);

    float v[C];
#pragma unroll
    for (int c = 0; c < C; c++) {
        v[c] = Aun[threadIdx.x * C + c];     // stride 21 (odd) -> conflict-free
        q[c * HW + p] = v[c];
        unp[c * HW + p] = v[c];
    }

    // spatial factors dedup'd: 9 statically-indexed values (bit-identical)
    float swl[9];
#pragma unroll
    for (int i = 0; i < 9; i++) swl[i] = expf(-(float)i * (1.0f / 51200.0f));

    // bilateral weights (bf16-rounded); denominator sums the SAME rounded vals
    int lrow0 = y - y0row + 2;                  // own pixel's Argb row (2 or 3)
    float r0 = Argb[lrow0 * (W * 3) + x * 3 + 0];
    float g0 = Argb[lrow0 * (W * 3) + x * 3 + 1];
    float b0 = Argb[lrow0 * (W * 3) + x * 3 + 2];
    float s = 0.f;
    int t = 0;
#pragma unroll
    for (int dy = -2; dy <= 2; dy++) {
#pragma unroll
        for (int dx = -2; dx <= 2; dx++, t++) {
            int sy = y - dy, sx = x - dx;
            float wv = 0.f;
            if (sy >= 0 && sy < H && sx >= 0 && sx < W) {
                int lr = sy - y0row + 2;        // 0..5, in-bounds by sy guard
                const float* rp = Argb + lr * (W * 3) + sx * 3;
                float dr = r0 - rp[0];
                float dg = g0 - rp[1];
                float db = b0 - rp[2];
                wv = swl[dy * dy + dx * dx] *
                     expf(-(dr * dr + dg * dg + db * db) * (1.0f / 18.0f));
            }
            u16 wu = f2bfu(wv);
            wtab[(size_t)t * HW + p] = wu;
            s += bfu2f(wu);
        }
    }
    inv_bn[p] = 1.0f / s;

    float fy = 0.f, fx = 0.f;
    for (int o = -6; o <= 6; o++) {
        if (y - o >= 0 && y - o < H) fy += gk[o + 6];
        if (x - o >= 0 && x - o < W) fx += gk[o + 6];
    }
    inv_sp[p] = 1.0f / (fy * fx);

    int vv = sp[x * W + y];   // sp_map transposed: sp[x][y]
    msum[p] = (vv == 5 || vv == 37 || vv == 81 || vv == 150 || vv == 230) ? 1.0f : 0.0f;

    __syncthreads();          // seq final
    bool eq = (seq != 0);
    if (bid == 0 && threadIdx.x == 0) mflag[0] = eq ? 1 : 0;

    // ---- fused ST for iteration 0: softmax(v) + M@sm -> t1 (t2 iff !eq) ----
    float mx = -1e30f;
#pragma unroll
    for (int c = 0; c < C; c++) mx = fmaxf(mx, v[c]);
    float ssum = 0.f;
#pragma unroll
    for (int c = 0; c < C; c++) {
        v[c] = expf(v[c] - mx);
        ssum += v[c];
    }
    float inv = 1.0f / ssum;
    float a1[C];
#pragma unroll
    for (int c = 0; c < C; c++) a1[c] = 0.f;
#pragma unroll
    for (int k = 0; k < C; k++) {
        float e = v[k];
#pragma unroll
        for (int c = 0; c < C; c++) a1[c] += sM1[c * C + k] * e;
    }
#pragma unroll
    for (int c = 0; c < C; c++) t1[c * HW + p] = f2bfu(a1[c] * inv);
    if (!eq) {                // general path only; skipped on graded instance
        float a2[C];
#pragma unroll
        for (int c = 0; c < C; c++) a2[c] = 0.f;
#pragma unroll
        for (int k = 0; k < C; k++) {
            float e = v[k];
#pragma unroll
            for (int c = 0; c < C; c++) a2[c] += sM2[c * C + k] * e;
        }
#pragma unroll
        for (int c = 0; c < C; c++) t2[c * HW + p] = f2bfu(a2[c] * inv);
    }
}

// fused softmax + 21x21 matmul(s) (iters 1..4). M via uniform s_loads.
// meq: single matmul + single bf16 store set (t2 == t1 on graded instance).
__global__ __launch_bounds__(256)
void k_ST(const float* __restrict__ q, const float* __restrict__ M1,
          const float* __restrict__ M2, const int* __restrict__ mflag,
          u16* __restrict__ t1, u16* __restrict__ t2) {
    int bid = blockIdx.x;                  // 576, XCD-swizzled
    int chunk = (bid & 7) * 72 + (bid >> 3);
    int p = chunk * 256 + threadIdx.x;
    bool meq = (mflag[0] != 0);            // uniform branch
    float v[C];
    float mx = -1e30f;
#pragma unroll
    for (int c = 0; c < C; c++) {
        v[c] = q[c * HW + p];
        mx = fmaxf(mx, v[c]);
    }
    float s = 0.f;
#pragma unroll
    for (int c = 0; c < C; c++) {
        v[c] = expf(v[c] - mx);
        s += v[c];
    }
    float inv = 1.0f / s;
    float a1[C];
#pragma unroll
    for (int c = 0; c < C; c++) a1[c] = 0.f;
#pragma unroll
    for (int k = 0; k < C; k++) {
        float e = v[k];
#pragma unroll
        for (int c = 0; c < C; c++) a1[c] += M1[c * C + k] * e;  // s_load
    }
#pragma unroll
    for (int c = 0; c < C; c++) t1[c * HW + p] = f2bfu(a1[c] * inv);
    if (!meq) {               // general path only; skipped on graded instance
        float a2[C];
#pragma unroll
        for (int c = 0; c < C; c++) a2[c] = 0.f;
#pragma unroll
        for (int k = 0; k < C; k++) {
            float e = v[k];
#pragma unroll
            for (int c = 0; c < C; c++) a2[c] += M2[c * C + k] * e;
        }
#pragma unroll
        for (int c = 0; c < C; c++) t2[c * HW + p] = f2bfu(a2[c] * inv);
    }
}

// fused separable blur (LDS) + bilateral + update.
// R6: (a) all 25 wtab loads issued at kernel entry (after the 3 staging
// loads) so they stay in flight across both barriers — the compiler cannot
// hoist them over __syncthreads itself; (b) staging is branchless: halo
// float4s are provably all-in or all-out of bounds (gx,W multiples of 4),
// so the 3 clamped loads issue back-to-back (one latency, not three).
__global__ __launch_bounds__(256)
void k_VF(const u16* __restrict__ t1, const u16* __restrict__ t2,
          const u16* __restrict__ wtab, const float* __restrict__ msum,
          const float* __restrict__ inv_sp, const float* __restrict__ inv_bn,
          const float* __restrict__ unp,
          const float* __restrict__ loww, const float* __restrict__ highw,
          const int* __restrict__ mflag,
          float* __restrict__ q, float* __restrict__ outp) {
    GKDEF;
    __shared__ float A[20 * 144];   // t1 halo tile; reused for t2 iff !meq
    __shared__ float B[8 * 144];    // blurV output
    int bid = blockIdx.x;           // grid 3024, XCD-swizzled
    int xcd = bid & 7;
    int idx = bid >> 3;
    int c   = idx % 21;
    int rem = idx / 21;
    int xt  = rem % 3;
    int ytl = rem / 3;
    int gyt = xcd * 6 + ytl;
    int x0 = xt * 128;
    int y0 = gyt * 8;
    bool meq = (mflag[0] != 0);     // uniform branch
    const u16* t1p = t1 + (size_t)c * HW;

    int row = threadIdx.x >> 5;
    int xq  = (threadIdx.x & 31) * 4;
    int y   = y0 + row;
    int x4  = x0 + xq;
    int p4  = y * W + x4;

    // ---- staging loads (3 slots, branchless clamped+select) ----
    int i0 = threadIdx.x, i1 = threadIdx.x + 256, i2 = threadIdx.x + 512;
    int r0_ = i0 / 36, q0_ = i0 - r0_ * 36;
    int r1_ = i1 / 36, q1_ = i1 - r1_ * 36;
    int r2_ = i2 / 36, q2_ = i2 - r2_ * 36;
    int gy0 = y0 - 6 + r0_, gx0 = x0 - 8 + q0_ * 4;
    int gy1 = y0 - 6 + r1_, gx1 = x0 - 8 + q1_ * 4;
    int gy2 = y0 - 6 + r2_, gx2 = x0 - 8 + q2_ * 4;
    bool ok0 = (gy0 >= 0) & (gy0 < H) & (gx0 >= 0) & (gx0 < W);
    bool ok1 = (gy1 >= 0) & (gy1 < H) & (gx1 >= 0) & (gx1 < W);
    bool ok2 = (gy2 >= 0) & (gy2 < H) & (gx2 >= 0) & (gx2 < W);
    ushort4 u0 = *(const ushort4*)(t1p + min(max(gy0, 0), H - 1) * W + min(max(gx0, 0), W - 4));
    ushort4 u1 = *(const ushort4*)(t1p + min(max(gy1, 0), H - 1) * W + min(max(gx1, 0), W - 4));
    ushort4 u2 = *(const ushort4*)(t1p + min(max(gy2, 0), H - 1) * W + min(max(gx2, 0), W - 4));

    // ---- issue all 25 bilateral-weight loads NOW (in flight across both
    // barriers; consumed only in the bilateral phase) ----
    ushort4 wu[25];
#pragma unroll
    for (int t = 0; t < 25; t++)
        wu[t] = *(const ushort4*)(wtab + (size_t)t * HW + p4);

    // ---- write staged halo (zero OOB slots), bf16 -> fp32 ----
    {
        float4 v;
        v.x = ok0 ? bfu2f(u0.x) : 0.f; v.y = ok0 ? bfu2f(u0.y) : 0.f;
        v.z = ok0 ? bfu2f(u0.z) : 0.f; v.w = ok0 ? bfu2f(u0.w) : 0.f;
        *(float4*)(A + r0_ * 144 + q0_ * 4) = v;
        v.x = ok1 ? bfu2f(u1.x) : 0.f; v.y = ok1 ? bfu2f(u1.y) : 0.f;
        v.z = ok1 ? bfu2f(u1.z) : 0.f; v.w = ok1 ? bfu2f(u1.w) : 0.f;
        *(float4*)(A + r1_ * 144 + q1_ * 4) = v;
        if (i2 < 20 * 36) {
            v.x = ok2 ? bfu2f(u2.x) : 0.f; v.y = ok2 ? bfu2f(u2.y) : 0.f;
            v.z = ok2 ? bfu2f(u2.z) : 0.f; v.w = ok2 ? bfu2f(u2.w) : 0.f;
            *(float4*)(A + r2_ * 144 + q2_ * 4) = v;
        }
    }
    __syncthreads();

    // ---- blurV (float4): B[r][c4..c4+3] = sum_d gk[d]*A[r+d][c4..c4+3] ----
    for (int i = threadIdx.x; i < 8 * 36; i += 256) {
        int r = i / 36, c4 = (i - r * 36) * 4;
        float ax = 0.f, ay = 0.f, az = 0.f, aw = 0.f;
#pragma unroll
        for (int d = 0; d < 13; d++) {
            const float4 av = *(const float4*)(A + (r + d) * 144 + c4);
            ax += gk[d] * av.x;
            ay += gk[d] * av.y;
            az += gk[d] * av.z;
            aw += gk[d] * av.w;
        }
        float4 o;
        o.x = ax; o.y = ay; o.z = az; o.w = aw;
        *(float4*)(B + r * 144 + c4) = o;
    }
    __syncthreads();

    // ---- blurH: 20-float window as 5 aligned b128 (conflict-free) ----
    float bw[20];
    {
        const float* bp = B + row * 144 + xq;
        *(float4*)(bw +  0) = *(const float4*)(bp +  0);
        *(float4*)(bw +  4) = *(const float4*)(bp +  4);
        *(float4*)(bw +  8) = *(const float4*)(bp +  8);
        *(float4*)(bw + 12) = *(const float4*)(bp + 12);
        *(float4*)(bw + 16) = *(const float4*)(bp + 16);
    }
    float sp_[4];
#pragma unroll
    for (int jj = 0; jj < 4; jj++) {
        float a = 0.f;
#pragma unroll
        for (int t = 0; t < 13; t++) a += gk[t] * bw[jj + t + 2];
        sp_[jj] = a;
    }

    int robase;   // bilateral row base in A
    if (meq) {
        robase = row + 6;     // t1 halo rows: gy = y0-6+r  -> r = row-dy+6
    } else {
        // ---- general path: stage t2 tile into A (after blurV barrier) ----
        const u16* t2p = t2 + (size_t)c * HW;
        for (int i = threadIdx.x; i < 12 * 36; i += 256) {
            int r = i / 36, q4 = i - r * 36;
            int gy = min(max(y0 - 2 + r, 0), H - 1);      // clamped; OOB wt 0
            int gx = min(max(x0 - 8 + q4 * 4, 0), W - 4); // clamped; OOB wt 0
            ushort4 u = *(const ushort4*)(t2p + gy * W + gx);
            float4 v;
            v.x = bfu2f(u.x); v.y = bfu2f(u.y); v.z = bfu2f(u.z); v.w = bfu2f(u.w);
            *(float4*)(A + r * 144 + q4 * 4) = v;
        }
        __syncthreads();
        robase = row + 2;     // t2 tile rows: gy = y0-2+r  -> r = row-dy+2
    }

    // hoist update-phase loads ahead of the bilateral FMA chain
    float lc = loww[c], hw_ = highw[0];
    float4 msv = *(const float4*)(msum + p4);
    float4 isv = *(const float4*)(inv_sp + p4);
    float4 ibv = *(const float4*)(inv_bn + p4);
    float4 unv = *(const float4*)(unp + (size_t)c * HW + p4);
    float* qp = q + (size_t)c * HW + p4;
    float4 qo4 = *(const float4*)qp;

    // ---- bilateral from LDS (wu long since resident) ----
    float bi[4] = {0.f, 0.f, 0.f, 0.f};
    int lb = xq + 8;                        // local col of x4 in the 144-tile
#pragma unroll
    for (int dy = -2; dy <= 2; dy++) {
        int r = robase - dy;
        float rr[12];
        float4 v0 = *(const float4*)(A + r * 144 + lb - 4);
        float4 v1 = *(const float4*)(A + r * 144 + lb);
        float4 v2 = *(const float4*)(A + r * 144 + lb + 4);
        rr[0] = v0.x; rr[1] = v0.y; rr[2]  = v0.z; rr[3]  = v0.w;
        rr[4] = v1.x; rr[5] = v1.y; rr[6]  = v1.z; rr[7]  = v1.w;
        rr[8] = v2.x; rr[9] = v2.y; rr[10] = v2.z; rr[11] = v2.w;
#pragma unroll
        for (int dx = -2; dx <= 2; dx++) {
            const ushort4 wv = wu[(dy + 2) * 5 + (dx + 2)];
            bi[0] += bfu2f(wv.x) * rr[0 - dx + 4];
            bi[1] += bfu2f(wv.y) * rr[1 - dx + 4];
            bi[2] += bfu2f(wv.z) * rr[2 - dx + 4];
            bi[3] += bfu2f(wv.w) * rr[3 - dx + 4];
        }
    }

    // ---- update: q/out = un - pairwise + superpixel closed form ----
    float msa[4] = {msv.x, msv.y, msv.z, msv.w};
    float isa[4] = {isv.x, isv.y, isv.z, isv.w};
    float iba[4] = {ibv.x, ibv.y, ibv.z, ibv.w};
    float qoa[4] = {qo4.x, qo4.y, qo4.z, qo4.w};
    float una[4] = {unv.x, unv.y, unv.z, unv.w};
    float outv[4];
    for (int jj = 0; jj < 4; jj++) {
        float pw = sp_[jj] * isa[jj] + bi[jj] * iba[jj];
        float qo = qoa[jj];
        float ft = (msa[jj] * qo + (NCLIQ - msa[jj])) / qo;
        float su = lc * ft + hw_ * (1.0f - ft);
        outv[jj] = una[jj] - pw + su;
    }
    if (outp) {   // last iteration: write final (H,W,C) layout directly
        for (int jj = 0; jj < 4; jj++)
            outp[(size_t)(p4 + jj) * C + c] = outv[jj];
    } else {
        float4 res;
        res.x = outv[0]; res.y = outv[1]; res.z = outv[2]; res.w = outv[3];
        *(float4*)qp = res;
    }
}

// ---- launch -----------------------------------------------------------------

extern "C" void kernel_launch(void* const* d_in, const int* in_sizes, int n_in,
                              void* d_out, int out_size, void* d_ws, size_t ws_size,
                              hipStream_t stream) {
    const float* un    = (const float*)d_in[0];
    const float* rgb   = (const float*)d_in[1];
    const int*   sp    = (const int*)d_in[2];
    const float* Wsp   = (const float*)d_in[3];
    const float* Wbi   = (const float*)d_in[4];
    const float* Cm    = (const float*)d_in[5];
    const float* loww  = (const float*)d_in[6];
    const float* highw = (const float*)d_in[7];
    float* out = (float*)d_out;

    // ws layout ~46.5 MB
    float* ws    = (float*)d_ws;
    float* q     = ws;                            // C*HW fp32
    float* unp   = q   + (size_t)C * HW;          // C*HW fp32
    float* msum  = unp + (size_t)C * HW;          // HW
    float* isp   = msum + HW;                     // HW
    float* ibn   = isp + HW;                      // HW
    float* M1    = ibn + HW;                      // C*C
    float* M2    = M1 + C * C;                    // C*C
    int*   mflag = (int*)(M2 + C * C);            // 1 (in old pad space)
    u16*   t1    = (u16*)(M2 + C * C + 6);        // C*HW bf16 (8B-aligned)
    u16*   t2    = t1 + (size_t)C * HW;           // C*HW bf16
    u16*   wtab  = t2 + (size_t)C * HW;           // 25*HW bf16

    dim3 blk(256);
    dim3 gpix(HW / 256);                 // 576
    dim3 gVF(3 * 48 * C);                // 3024, 1-D swizzled

    // prep includes iteration 0's ST
    k_prep<<<gpix, blk, 0, stream>>>(un, rgb, sp, Wsp, Wbi, Cm,
                                     q, unp, wtab, msum, isp, ibn, M1, M2,
                                     mflag, t1, t2);
    for (int it = 0; it < 5; it++) {
        k_VF<<<gVF, blk, 0, stream>>>(t1, t2, wtab, msum, isp, ibn,
                                      unp, loww, highw, mflag, q,
                                      (it == 4) ? out : (float*)nullptr);
        if (it < 4)
            k_ST<<<gpix, blk, 0, stream>>>(q, M1, M2, mflag, t1, t2);
    }
}